// Round 1
// baseline (336.737 us; speedup 1.0000x reference)
//
#include <hip/hip_runtime.h>
#include <stdint.h>

#define N_NODES 100000
#define N_FEAT 128
#define N_EDGES 3200000

// ---------- bf16 helpers (manual, avoids hip_bf16.h API drift) ----------
static __device__ __forceinline__ unsigned short f2bf(float f) {
    unsigned int u = __float_as_uint(f);
    u += 0x7FFFu + ((u >> 16) & 1u);   // RNE (inputs are normal randoms; no NaN care)
    return (unsigned short)(u >> 16);
}

typedef __bf16 bf16x8 __attribute__((ext_vector_type(8)));
typedef float f32x4 __attribute__((ext_vector_type(4)));

// ---------- Kernel 1: x fp32 -> bf16 ----------
__global__ void k_convert_x(const float* __restrict__ x, unsigned short* __restrict__ xb) {
    long long i = (long long)(blockIdx.x * blockDim.x + threadIdx.x) * 4;
    if (i >= (long long)N_NODES * N_FEAT) return;
    float4 v = *(const float4*)(x + i);
    ushort4 o;
    o.x = f2bf(v.x); o.y = f2bf(v.y); o.z = f2bf(v.z); o.w = f2bf(v.w);
    *(ushort4*)(xb + i) = o;
}

// ---------- Kernel 1b: filters [K][N] fp32 -> Ftrans bf16 [N][K] ----------
__global__ void k_convert_f(const float* __restrict__ f, unsigned short* __restrict__ fT) {
    int i = blockIdx.x * blockDim.x + threadIdx.x;   // i = k*128 + n
    if (i >= N_FEAT * N_FEAT) return;
    int k = i >> 7, n = i & 127;
    fT[n * N_FEAT + k] = f2bf(f[i]);
}

// ---------- Kernel 2: CSR row pointers from sorted edge_dst ----------
__global__ void k_rowptr(const int* __restrict__ dst, int* __restrict__ row_ptr) {
    int d = blockIdx.x * blockDim.x + threadIdx.x;
    if (d > N_NODES) return;
    int lo = 0, hi = N_EDGES;
    while (lo < hi) {                 // lower_bound(dst, d)
        int mid = (lo + hi) >> 1;
        if (dst[mid] < d) lo = mid + 1; else hi = mid;
    }
    row_ptr[d] = lo;
}

// ---------- Kernel 3: per-node weighted aggregation of bf16 x ----------
// one wave per node; lane holds 2 features (bf16x2 = 4B); fp32 accumulate.
__global__ __launch_bounds__(256) void k_aggregate(
        const unsigned short* __restrict__ xb,
        const int* __restrict__ src,
        const float* __restrict__ w,
        const int* __restrict__ row_ptr,
        unsigned short* __restrict__ aggb) {
    int wave = threadIdx.x >> 6, lane = threadIdx.x & 63;
    int node = blockIdx.x * 4 + wave;
    if (node >= N_NODES) return;
    int start = row_ptr[node], end = row_ptr[node + 1];
    float ax = 0.f, ay = 0.f;
    const unsigned int* x2 = (const unsigned int*)xb;   // bf16x2 view
    for (int e0 = start; e0 < end; e0 += 64) {
        int e = e0 + lane;
        int s = 0; float we = 0.f;
        if (e < end) { s = src[e]; we = w[e]; }          // coalesced metadata
        int cnt = min(64, end - e0);
        for (int j = 0; j < cnt; ++j) {
            int   sj = __shfl(s, j);
            float wj = __shfl(we, j);
            unsigned int v = x2[(long long)sj * 64 + lane];  // 256B row / wave
            float v0 = __uint_as_float(v << 16);
            float v1 = __uint_as_float(v & 0xFFFF0000u);
            ax = fmaf(wj, v0, ax);
            ay = fmaf(wj, v1, ay);
        }
    }
    unsigned int o = ((unsigned int)f2bf(ay) << 16) | (unsigned int)f2bf(ax);
    ((unsigned int*)aggb)[(long long)node * 64 + lane] = o;
}

// ---------- Kernel 4: out = agg_bf16 @ F  (MFMA bf16, single K pass) ----------
#define LDA 136   // 128 + 8 bf16 pad -> row stride 272B, breaks bank aliasing

__global__ __launch_bounds__(256, 2) void k_gemm(
        const unsigned short* __restrict__ A,   // [M][128] bf16 (agg)
        const unsigned short* __restrict__ BT,  // [128][128] bf16, n-major (F^T)
        float* __restrict__ C) {                // [M][128] fp32
    __shared__ unsigned short Abuf[128 * LDA];
    __shared__ unsigned short Bbuf[128 * LDA];
    int t = threadIdx.x;
    int tileM = blockIdx.x * 128;

    // stage A tile + B (each thread: 8 chunks of 8 bf16 = 16B, coalesced)
    for (int i = 0; i < 8; ++i) {
        int c = t + i * 256;
        int r = c >> 4, c8 = c & 15;
        int grow = tileM + r;
        if (grow >= N_NODES) grow = N_NODES - 1;        // clamp; tail rows unused
        uint4 va = *(const uint4*)(A + (long long)grow * 128 + c8 * 8);
        *(uint4*)(Abuf + r * LDA + c8 * 8) = va;
        uint4 vb = *(const uint4*)(BT + r * 128 + c8 * 8);
        *(uint4*)(Bbuf + r * LDA + c8 * 8) = vb;
    }
    __syncthreads();

    int wave = t >> 6, lane = t & 63;
    int wm = (wave >> 1) * 64, wn = (wave & 1) * 64;    // 64x64 per wave
    int m15 = lane & 15, q = lane >> 4;

    f32x4 acc[4][4];
    for (int i = 0; i < 4; ++i)
        for (int j = 0; j < 4; ++j)
            acc[i][j] = f32x4{0.f, 0.f, 0.f, 0.f};

    for (int kk = 0; kk < 128; kk += 32) {
        bf16x8 a[4], b[4];
        for (int i = 0; i < 4; ++i)
            a[i] = *(const bf16x8*)(Abuf + (wm + i * 16 + m15) * LDA + kk + q * 8);
        for (int j = 0; j < 4; ++j)
            b[j] = *(const bf16x8*)(Bbuf + (wn + j * 16 + m15) * LDA + kk + q * 8);
        for (int i = 0; i < 4; ++i)
            for (int j = 0; j < 4; ++j)
                acc[i][j] = __builtin_amdgcn_mfma_f32_16x16x32_bf16(a[i], b[j], acc[i][j], 0, 0, 0);
    }

    // epilogue: D row = q*4 + reg, col = lane&15 (verified m89/m91 layout)
    for (int i = 0; i < 4; ++i) {
        int rowbase = tileM + wm + i * 16 + q * 4;
        for (int j = 0; j < 4; ++j) {
            int col = wn + j * 16 + m15;
            for (int r = 0; r < 4; ++r) {
                int grow = rowbase + r;
                if (grow < N_NODES)
                    C[(long long)grow * 128 + col] = acc[i][j][r];
            }
        }
    }
}

extern "C" void kernel_launch(void* const* d_in, const int* in_sizes, int n_in,
                              void* d_out, int out_size, void* d_ws, size_t ws_size,
                              hipStream_t stream) {
    const float* x        = (const float*)d_in[0];
    const float* filters  = (const float*)d_in[1];
    const int*   edge_src = (const int*)d_in[2];
    const int*   edge_dst = (const int*)d_in[3];
    const float* edge_w   = (const float*)d_in[4];
    float* out = (float*)d_out;

    char* ws = (char*)d_ws;
    unsigned short* xb   = (unsigned short*)(ws);                          // 25.6 MB
    unsigned short* fT   = (unsigned short*)(ws + 26ll * 1024 * 1024);     // 32 KB
    unsigned short* aggb = (unsigned short*)(ws + 27ll * 1024 * 1024);     // 25.6 MB
    int*            rp   = (int*)           (ws + 54ll * 1024 * 1024);     // 400 KB

    hipLaunchKernelGGL(k_convert_x, dim3(12500), dim3(256), 0, stream, x, xb);
    hipLaunchKernelGGL(k_convert_f, dim3(64),    dim3(256), 0, stream, filters, fT);
    hipLaunchKernelGGL(k_rowptr,    dim3(391),   dim3(256), 0, stream, edge_dst, rp);
    hipLaunchKernelGGL(k_aggregate, dim3(25000), dim3(256), 0, stream, xb, edge_src, edge_w, rp, aggb);
    hipLaunchKernelGGL(k_gemm,      dim3(782),   dim3(256), 0, stream, aggb, fT, out);
}

// Round 2
// 246.921 us; speedup vs baseline: 1.3637x; 1.3637x over previous
//
#include <hip/hip_runtime.h>
#include <stdint.h>

#define N_NODES 100000
#define N_FEAT 128
#define N_EDGES 3200000

// ---------- bf16 helpers ----------
static __device__ __forceinline__ unsigned short f2bf(float f) {
    unsigned int u = __float_as_uint(f);
    u += 0x7FFFu + ((u >> 16) & 1u);   // RNE
    return (unsigned short)(u >> 16);
}

typedef __bf16 bf16x8 __attribute__((ext_vector_type(8)));
typedef float f32x4 __attribute__((ext_vector_type(4)));

// ---------- Kernel 1: x fp32 -> bf16 ----------
__global__ void k_convert_x(const float* __restrict__ x, unsigned short* __restrict__ xb) {
    long long i = (long long)(blockIdx.x * blockDim.x + threadIdx.x) * 4;
    if (i >= (long long)N_NODES * N_FEAT) return;
    float4 v = *(const float4*)(x + i);
    ushort4 o;
    o.x = f2bf(v.x); o.y = f2bf(v.y); o.z = f2bf(v.z); o.w = f2bf(v.w);
    *(ushort4*)(xb + i) = o;
}

// ---------- Kernel 1b: filters [K][N] fp32 -> F^T bf16 [N][K] ----------
__global__ void k_convert_f(const float* __restrict__ f, unsigned short* __restrict__ fT) {
    int i = blockIdx.x * blockDim.x + threadIdx.x;   // i = k*128 + n
    if (i >= N_FEAT * N_FEAT) return;
    int k = i >> 7, n = i & 127;
    fT[n * N_FEAT + k] = f2bf(f[i]);
}

// ---------- Kernel 2: CSR row pointers, edge-parallel scatter ----------
// row_ptr[d] = lower_bound(dst, d). dst is sorted. Total writes = N+1.
__global__ void k_rowptr(const int* __restrict__ dst, int* __restrict__ row_ptr) {
    int e = blockIdx.x * blockDim.x + threadIdx.x;
    if (e >= N_EDGES) return;
    int dcur = dst[e];
    if (e == 0) {
        for (int d = 0; d <= dcur; ++d) row_ptr[d] = 0;
    } else {
        int dprev = dst[e - 1];
        for (int d = dprev + 1; d <= dcur; ++d) row_ptr[d] = e;
    }
    if (e == N_EDGES - 1) {
        for (int d = dcur + 1; d <= N_NODES; ++d) row_ptr[d] = N_EDGES;
    }
}

// ---------- Kernel 3: per-node weighted aggregation of bf16 x ----------
// One wave per node. Metadata staged per-64-edge-chunk into wave-private LDS
// as interleaved (src,w); inner loop unrolled x8 so 8 gathers are in flight
// before the first FMA waits. Chunk padded to x8 with w=0 (src=0 row, cache-hot).
__global__ __launch_bounds__(256) void k_aggregate(
        const unsigned short* __restrict__ xb,
        const int* __restrict__ src,
        const float* __restrict__ w,
        const int* __restrict__ row_ptr,
        unsigned short* __restrict__ aggb) {
    __shared__ uint2 smeta[4][64];
    int wave = threadIdx.x >> 6, lane = threadIdx.x & 63;
    int node = blockIdx.x * 4 + wave;
    if (node >= N_NODES) return;
    int start = row_ptr[node], end = row_ptr[node + 1];
    float ax = 0.f, ay = 0.f;
    const unsigned int* x2 = (const unsigned int*)xb;   // bf16x2 view

    for (int e0 = start; e0 < end; e0 += 64) {
        int e = e0 + lane;
        uint2 m = make_uint2(0u, 0u);                    // (src=0, w=0) pad
        if (e < end) { m.x = (unsigned int)src[e]; m.y = __float_as_uint(w[e]); }
        smeta[wave][lane] = m;                           // wave-private; no barrier
        int cnt8 = (min(64, end - e0) + 7) & ~7;
        for (int j = 0; j < cnt8; j += 8) {
            unsigned int vv[8]; float wj[8];
#pragma unroll
            for (int u = 0; u < 8; ++u) {
                uint2 mm = smeta[wave][j + u];           // broadcast ds_read_b64
                wj[u] = __uint_as_float(mm.y);
                vv[u] = x2[(long long)mm.x * 64 + lane]; // 256B row / wave
            }
#pragma unroll
            for (int u = 0; u < 8; ++u) {
                float v0 = __uint_as_float(vv[u] << 16);
                float v1 = __uint_as_float(vv[u] & 0xFFFF0000u);
                ax = fmaf(wj[u], v0, ax);
                ay = fmaf(wj[u], v1, ay);
            }
        }
    }
    unsigned int o = ((unsigned int)f2bf(ay) << 16) | (unsigned int)f2bf(ax);
    ((unsigned int*)aggb)[(long long)node * 64 + lane] = o;
}

// ---------- Kernel 4: out = agg_bf16 @ F  (MFMA bf16, single K pass) ----------
#define LDA 136   // 128 + 8 bf16 pad

__global__ __launch_bounds__(256, 2) void k_gemm(
        const unsigned short* __restrict__ A,   // [M][128] bf16 (agg)
        const unsigned short* __restrict__ BT,  // [128][128] bf16, n-major (F^T)
        float* __restrict__ C) {                // [M][128] fp32
    __shared__ unsigned short Abuf[128 * LDA];
    __shared__ unsigned short Bbuf[128 * LDA];
    int t = threadIdx.x;
    int tileM = blockIdx.x * 128;

    for (int i = 0; i < 8; ++i) {
        int c = t + i * 256;
        int r = c >> 4, c8 = c & 15;
        int grow = tileM + r;
        if (grow >= N_NODES) grow = N_NODES - 1;        // clamp; tail rows unused
        uint4 va = *(const uint4*)(A + (long long)grow * 128 + c8 * 8);
        *(uint4*)(Abuf + r * LDA + c8 * 8) = va;
        uint4 vb = *(const uint4*)(BT + r * 128 + c8 * 8);
        *(uint4*)(Bbuf + r * LDA + c8 * 8) = vb;
    }
    __syncthreads();

    int wave = t >> 6, lane = t & 63;
    int wm = (wave >> 1) * 64, wn = (wave & 1) * 64;    // 64x64 per wave
    int m15 = lane & 15, q = lane >> 4;

    f32x4 acc[4][4];
    for (int i = 0; i < 4; ++i)
        for (int j = 0; j < 4; ++j)
            acc[i][j] = f32x4{0.f, 0.f, 0.f, 0.f};

    for (int kk = 0; kk < 128; kk += 32) {
        bf16x8 a[4], b[4];
        for (int i = 0; i < 4; ++i)
            a[i] = *(const bf16x8*)(Abuf + (wm + i * 16 + m15) * LDA + kk + q * 8);
        for (int j = 0; j < 4; ++j)
            b[j] = *(const bf16x8*)(Bbuf + (wn + j * 16 + m15) * LDA + kk + q * 8);
        for (int i = 0; i < 4; ++i)
            for (int j = 0; j < 4; ++j)
                acc[i][j] = __builtin_amdgcn_mfma_f32_16x16x32_bf16(a[i], b[j], acc[i][j], 0, 0, 0);
    }

    // D row = q*4 + reg, col = lane&15 (m89/m91 layout)
    for (int i = 0; i < 4; ++i) {
        int rowbase = tileM + wm + i * 16 + q * 4;
        for (int j = 0; j < 4; ++j) {
            int col = wn + j * 16 + m15;
            for (int r = 0; r < 4; ++r) {
                int grow = rowbase + r;
                if (grow < N_NODES)
                    C[(long long)grow * 128 + col] = acc[i][j][r];
            }
        }
    }
}

extern "C" void kernel_launch(void* const* d_in, const int* in_sizes, int n_in,
                              void* d_out, int out_size, void* d_ws, size_t ws_size,
                              hipStream_t stream) {
    const float* x        = (const float*)d_in[0];
    const float* filters  = (const float*)d_in[1];
    const int*   edge_src = (const int*)d_in[2];
    const int*   edge_dst = (const int*)d_in[3];
    const float* edge_w   = (const float*)d_in[4];
    float* out = (float*)d_out;

    char* ws = (char*)d_ws;
    unsigned short* xb   = (unsigned short*)(ws);                          // 25.6 MB
    unsigned short* fT   = (unsigned short*)(ws + 26ll * 1024 * 1024);     // 32 KB
    unsigned short* aggb = (unsigned short*)(ws + 27ll * 1024 * 1024);     // 25.6 MB
    int*            rp   = (int*)           (ws + 54ll * 1024 * 1024);     // 400 KB

    hipLaunchKernelGGL(k_convert_x, dim3(12500), dim3(256), 0, stream, x, xb);
    hipLaunchKernelGGL(k_convert_f, dim3(64),    dim3(256), 0, stream, filters, fT);
    hipLaunchKernelGGL(k_rowptr,    dim3(12500), dim3(256), 0, stream, edge_dst, rp);
    hipLaunchKernelGGL(k_aggregate, dim3(25000), dim3(256), 0, stream, xb, edge_src, edge_w, rp, aggb);
    hipLaunchKernelGGL(k_gemm,      dim3(782),   dim3(256), 0, stream, aggb, fT, out);
}